// Round 3
// baseline (225.808 us; speedup 1.0000x reference)
//
#include <hip/hip_runtime.h>
#include <hip/hip_bf16.h>
#include <stdint.h>

#define NUM_IN  2048   // K
#define NUM_OUT 8192   // N
#define BATCH   4096   // M
#define SD      5

#define BM 256
#define BN 256
#define BK 32
#define NT (NUM_IN / BK)     // 64 K-tiles
#define BUFE (BM * BK)       // 8192 elements per buffer per operand

typedef __bf16 bf16x8 __attribute__((ext_vector_type(8)));
typedef float  f32x16 __attribute__((ext_vector_type(16)));
typedef unsigned short ushort_t;
typedef ushort_t ushort8 __attribute__((ext_vector_type(8)));

static __device__ __forceinline__ ushort_t bf16_bits(float f) {
  __hip_bfloat16 h = __float2bfloat16(f);
  ushort_t u;
  __builtin_memcpy(&u, &h, 2);
  return u;
}

// ---------- inputs f32 -> bf16 (vectorized) ----------
__global__ __launch_bounds__(256) void cvt_kernel(const float* __restrict__ x,
                                                  ushort_t* __restrict__ y) {
  const int i = (blockIdx.x * 256 + threadIdx.x) * 8;
  float4 v0 = *reinterpret_cast<const float4*>(x + i);
  float4 v1 = *reinterpret_cast<const float4*>(x + i + 4);
  ushort8 o;
  o[0] = bf16_bits(v0.x); o[1] = bf16_bits(v0.y);
  o[2] = bf16_bits(v0.z); o[3] = bf16_bits(v0.w);
  o[4] = bf16_bits(v1.x); o[5] = bf16_bits(v1.y);
  o[6] = bf16_bits(v1.z); o[7] = bf16_bits(v1.w);
  *reinterpret_cast<ushort8*>(y + i) = o;
}

// ---------- W^T generation: one block per n, 8 k per thread, float4 loads ----------
__global__ __launch_bounds__(256) void genw_kernel(
    const float* __restrict__ in_pos, const float* __restrict__ out_pos,
    const float* __restrict__ init_in, const float* __restrict__ init_out,
    ushort_t* __restrict__ Wt) {
  const int n  = blockIdx.x;
  const int k0 = threadIdx.x * 8;

  float ip[40], iip[40];
#pragma unroll
  for (int j = 0; j < 10; ++j) {
    float4 v = *reinterpret_cast<const float4*>(in_pos + k0 * SD + j * 4);
    ip[j * 4 + 0] = v.x; ip[j * 4 + 1] = v.y;
    ip[j * 4 + 2] = v.z; ip[j * 4 + 3] = v.w;
    float4 u = *reinterpret_cast<const float4*>(init_in + k0 * SD + j * 4);
    iip[j * 4 + 0] = u.x; iip[j * 4 + 1] = u.y;
    iip[j * 4 + 2] = u.z; iip[j * 4 + 3] = u.w;
  }
  float op[SD], iop[SD];
#pragma unroll
  for (int d = 0; d < SD; ++d) {
    op[d]  = out_pos[n * SD + d];
    iop[d] = init_out[n * SD + d];
  }
  ushort8 o;
#pragma unroll
  for (int i = 0; i < 8; ++i) {
    float d1 = 0.f, d0 = 0.f;
#pragma unroll
    for (int d = 0; d < SD; ++d) {
      float a = ip[i * SD + d] - op[d];
      float b = iip[i * SD + d] - iop[d];
      d1 += a * a;
      d0 += b * b;
    }
    o[i] = bf16_bits(sqrtf(d1) - sqrtf(d0));
  }
  *reinterpret_cast<ushort8*>(Wt + (size_t)n * NUM_IN + k0) = o;
}

// ---------- GEMM: C[M][N] = A[M][K] * Bt[N][K]^T + bias ----------
// 256x256 tile, BK=32, ring-4 LDS buffers, prefetch lead 2 K-tiles,
// ONE barrier + counted vmcnt(4) per iteration (never drains),
// mfma_f32_32x32x16_bf16, conflict-free chunk-XOR swizzle.
__global__ __launch_bounds__(512, 2) void gemm_kernel(
    const ushort_t* __restrict__ A,    // [M][K] bf16
    const ushort_t* __restrict__ Bt,   // [N][K] bf16
    const float* __restrict__ bias,    // [N]
    float* __restrict__ C) {           // [M][N] f32
  __shared__ __align__(16) ushort_t sA[4 * BUFE];   // 64 KiB
  __shared__ __align__(16) ushort_t sB[4 * BUFE];   // 64 KiB

  const int tid = threadIdx.x;
  const int w   = tid >> 6;          // 0..7
  const int l   = tid & 63;
  const int wm  = w >> 2;            // 0..1  (M half)
  const int wn  = w & 3;             // 0..3  (N quarter)

  // bijective XCD swizzle: 512 blocks, 64 per XCD
  const int orig = blockIdx.x;
  const int lin  = (orig & 7) * 64 + (orig >> 3);
  const int bx   = lin >> 4;         // 0..31  N-block
  const int by   = lin & 15;         // 0..15  M-block
  const int m0   = by * BM;
  const int n0   = bx * BN;

  // ---- fragment read offsets (elements), swizzle folded per-lane ----
  // logical chunk for k-slice ks: c = ks*2 + (l>>5); stored at c ^ ((row>>1)&3)
  // row base multiples of 32 -> XOR term is lane-only: (l>>1)&3
  const int rA  = l & 31;
  const int hi  = l >> 5;            // 0..1
  const int swz = (l >> 1) & 3;
  const int aoff0 = (wm * 128 + rA) * BK + ((0 + hi) ^ swz) * 8;
  const int aoff1 = (wm * 128 + rA) * BK + ((2 + hi) ^ swz) * 8;
  const int boff0 = (wn * 64 + rA) * BK + ((0 + hi) ^ swz) * 8;
  const int boff1 = (wn * 64 + rA) * BK + ((2 + hi) ^ swz) * 8;

  // ---- staging geometry: idx = tid + i*512 covers (row = idx>>2, cp = idx&3)
  // source chunk c = cp ^ ((row>>1)&3) = cp ^ ((idx>>3)&3); LDS dest linear idx*8
  const int idx0 = tid, idx1 = tid + 512;
  const int c0 = (idx0 & 3) ^ ((idx0 >> 3) & 3);
  const int c1 = (idx1 & 3) ^ ((idx1 >> 3) & 3);
  const ushort_t* gA0 = A  + (size_t)(m0 + (idx0 >> 2)) * NUM_IN + c0 * 8;
  const ushort_t* gA1 = A  + (size_t)(m0 + (idx1 >> 2)) * NUM_IN + c1 * 8;
  const ushort_t* gB0 = Bt + (size_t)(n0 + (idx0 >> 2)) * NUM_IN + c0 * 8;
  const ushort_t* gB1 = Bt + (size_t)(n0 + (idx1 >> 2)) * NUM_IN + c1 * 8;
  const int ldsw = w * 512;          // wave-uniform base (elements)

#define GLDS(src, dst)                                                         \
  __builtin_amdgcn_global_load_lds(                                            \
      reinterpret_cast<const __attribute__((address_space(1))) uint32_t*>(     \
          (uintptr_t)(src)),                                                   \
      reinterpret_cast<__attribute__((address_space(3))) uint32_t*>(           \
          (uintptr_t)(dst)),                                                   \
      16, 0, 0)

#define STAGE(bs, kt)                                                          \
  {                                                                            \
    GLDS(gA0 + (kt), &sA[(bs) * BUFE + ldsw]);                                 \
    GLDS(gA1 + (kt), &sA[(bs) * BUFE + ldsw + 4096]);                          \
    GLDS(gB0 + (kt), &sB[(bs) * BUFE + ldsw]);                                 \
    GLDS(gB1 + (kt), &sB[(bs) * BUFE + ldsw + 4096]);                          \
  }

  f32x16 acc[4][2];
#pragma unroll
  for (int i = 0; i < 4; ++i)
#pragma unroll
    for (int j = 0; j < 2; ++j)
#pragma unroll
      for (int r = 0; r < 16; ++r) acc[i][j][r] = 0.f;

  // ---- prologue: stage tiles 0,1; wait tile 0; 4 loads stay in flight ----
  STAGE(0, 0)
  STAGE(1, BK)
  asm volatile("s_waitcnt vmcnt(4)" ::: "memory");
  __builtin_amdgcn_s_barrier();
  __builtin_amdgcn_sched_barrier(0);

#pragma unroll 1
  for (int t = 0; t < NT; ++t) {
    const int bufo = (t & 3) * BUFE;
    bf16x8 a[4][2], b[2][2];
#pragma unroll
    for (int mi = 0; mi < 4; ++mi) {
      a[mi][0] = *reinterpret_cast<const bf16x8*>(&sA[bufo + aoff0 + mi * 1024]);
      a[mi][1] = *reinterpret_cast<const bf16x8*>(&sA[bufo + aoff1 + mi * 1024]);
    }
#pragma unroll
    for (int ni = 0; ni < 2; ++ni) {
      b[ni][0] = *reinterpret_cast<const bf16x8*>(&sB[bufo + boff0 + ni * 1024]);
      b[ni][1] = *reinterpret_cast<const bf16x8*>(&sB[bufo + boff1 + ni * 1024]);
    }
    if (t < NT - 2) {
      STAGE((t + 2) & 3, (t + 2) * BK)
    }
    __builtin_amdgcn_s_setprio(1);
#pragma unroll
    for (int mi = 0; mi < 4; ++mi)
#pragma unroll
      for (int ni = 0; ni < 2; ++ni) {
        acc[mi][ni] = __builtin_amdgcn_mfma_f32_32x32x16_bf16(
            a[mi][0], b[ni][0], acc[mi][ni], 0, 0, 0);
        acc[mi][ni] = __builtin_amdgcn_mfma_f32_32x32x16_bf16(
            a[mi][1], b[ni][1], acc[mi][ni], 0, 0, 0);
      }
    __builtin_amdgcn_s_setprio(0);
    if (t < NT - 2) {
      asm volatile("s_waitcnt vmcnt(4)" ::: "memory");  // tile t+1 landed; t+2 flying
    } else {
      asm volatile("s_waitcnt vmcnt(0)" ::: "memory");  // tail drain
    }
    __builtin_amdgcn_s_barrier();
    __builtin_amdgcn_sched_barrier(0);
  }

  // ---- epilogue: C = acc + bias ----
  // D layout (32x32): col = l&31, row = (reg&3) + 8*(reg>>2) + 4*(l>>5)
  const int crow = m0 + wm * 128 + 4 * hi;
  const int ccol = n0 + wn * 64 + rA;
#pragma unroll
  for (int ni = 0; ni < 2; ++ni) {
    const float bi = bias[ccol + ni * 32];
#pragma unroll
    for (int mi = 0; mi < 4; ++mi) {
#pragma unroll
      for (int reg = 0; reg < 16; ++reg) {
        const int r = crow + mi * 32 + (reg & 3) + 8 * (reg >> 2);
        C[(size_t)r * NUM_OUT + ccol + ni * 32] = acc[mi][ni][reg] + bi;
      }
    }
  }
#undef STAGE
#undef GLDS
}

extern "C" void kernel_launch(void* const* d_in, const int* in_sizes, int n_in,
                              void* d_out, int out_size, void* d_ws, size_t ws_size,
                              hipStream_t stream) {
  const float* inputs   = (const float*)d_in[0];  // [4096,2048]
  const float* init_in  = (const float*)d_in[1];  // [2048,1,5]
  const float* init_out = (const float*)d_in[2];  // [1,8192,5]
  const float* in_pos   = (const float*)d_in[3];  // [2048,1,5]
  const float* out_pos  = (const float*)d_in[4];  // [1,8192,5]
  const float* biases   = (const float*)d_in[5];  // [8192]
  float* out = (float*)d_out;                     // [4096,8192]

  ushort_t* Abf = (ushort_t*)d_ws;
  ushort_t* Wt  = (ushort_t*)((char*)d_ws + (size_t)BATCH * NUM_IN * 2);

  cvt_kernel<<<(BATCH * NUM_IN) / (256 * 8), 256, 0, stream>>>(inputs, Abf);
  genw_kernel<<<NUM_OUT, 256, 0, stream>>>(
      in_pos, out_pos, init_in, init_out, Wt);
  gemm_kernel<<<(BATCH / BM) * (NUM_OUT / BN), 512, 0, stream>>>(
      Abf, Wt, biases, out);
}

// Round 4
// 185.290 us; speedup vs baseline: 1.2187x; 1.2187x over previous
//
#include <hip/hip_runtime.h>
#include <hip/hip_bf16.h>
#include <stdint.h>

#define NUM_IN  2048   // K
#define NUM_OUT 8192   // N
#define BATCH   4096   // M
#define SD      5

#define BM 256
#define BN 256
#define BK 32
#define NT (NUM_IN / BK)     // 64 K-tiles
#define BUFE (BM * BK)       // 8192 elements per ring buffer per operand

typedef __bf16 bf16x8 __attribute__((ext_vector_type(8)));
typedef float  f32x16 __attribute__((ext_vector_type(16)));
typedef unsigned short ushort_t;
typedef ushort_t ushort8 __attribute__((ext_vector_type(8)));

static __device__ __forceinline__ ushort_t bf16_bits(float f) {
  __hip_bfloat16 h = __float2bfloat16(f);
  ushort_t u;
  __builtin_memcpy(&u, &h, 2);
  return u;
}

// ---------- inputs f32 -> bf16 (vectorized) ----------
__global__ __launch_bounds__(256) void cvt_kernel(const float* __restrict__ x,
                                                  ushort_t* __restrict__ y) {
  const int i = (blockIdx.x * 256 + threadIdx.x) * 8;
  float4 v0 = *reinterpret_cast<const float4*>(x + i);
  float4 v1 = *reinterpret_cast<const float4*>(x + i + 4);
  ushort8 o;
  o[0] = bf16_bits(v0.x); o[1] = bf16_bits(v0.y);
  o[2] = bf16_bits(v0.z); o[3] = bf16_bits(v0.w);
  o[4] = bf16_bits(v1.x); o[5] = bf16_bits(v1.y);
  o[6] = bf16_bits(v1.z); o[7] = bf16_bits(v1.w);
  *reinterpret_cast<ushort8*>(y + i) = o;
}

// ---------- W^T generation ----------
// 512 blocks x 16 n each. in_pos/init_in staged in LDS (coalesced), 2 blocks/CU.
__global__ __launch_bounds__(256) void genw_kernel(
    const float* __restrict__ in_pos, const float* __restrict__ out_pos,
    const float* __restrict__ init_in, const float* __restrict__ init_out,
    ushort_t* __restrict__ Wt) {
  __shared__ float s_ip[NUM_IN * SD];    // 40 KB
  __shared__ float s_iip[NUM_IN * SD];   // 40 KB
  const int tid = threadIdx.x;
#pragma unroll
  for (int i = 0; i < 10; ++i) {
    const int idx = i * 1024 + tid * 4;
    *reinterpret_cast<float4*>(&s_ip[idx]) =
        *reinterpret_cast<const float4*>(in_pos + idx);
    *reinterpret_cast<float4*>(&s_iip[idx]) =
        *reinterpret_cast<const float4*>(init_in + idx);
  }
  __syncthreads();

  const int n  = blockIdx.x * 16 + (tid >> 4);
  const int kg = tid & 15;
  float op[SD], iop[SD];
#pragma unroll
  for (int d = 0; d < SD; ++d) {
    op[d]  = out_pos[n * SD + d];
    iop[d] = init_out[n * SD + d];
  }
#pragma unroll 1
  for (int kb = 0; kb < 16; ++kb) {
    const int k0 = kb * 128 + kg * 8;
    float buf[40], ibuf[40];
#pragma unroll
    for (int j = 0; j < 10; ++j) {
      float4 v = *reinterpret_cast<const float4*>(&s_ip[k0 * SD + j * 4]);
      buf[4 * j + 0] = v.x; buf[4 * j + 1] = v.y;
      buf[4 * j + 2] = v.z; buf[4 * j + 3] = v.w;
      float4 u = *reinterpret_cast<const float4*>(&s_iip[k0 * SD + j * 4]);
      ibuf[4 * j + 0] = u.x; ibuf[4 * j + 1] = u.y;
      ibuf[4 * j + 2] = u.z; ibuf[4 * j + 3] = u.w;
    }
    ushort8 o;
#pragma unroll
    for (int i = 0; i < 8; ++i) {
      float d1 = 0.f, d0 = 0.f;
#pragma unroll
      for (int d = 0; d < SD; ++d) {
        float a = buf[i * SD + d] - op[d];
        float b = ibuf[i * SD + d] - iop[d];
        d1 += a * a;
        d0 += b * b;
      }
      o[i] = bf16_bits(sqrtf(d1) - sqrtf(d0));
    }
    *reinterpret_cast<ushort8*>(Wt + (size_t)n * NUM_IN + k0) = o;
  }
}

// ---------- GEMM: C[M][N] = A[M][K] * Bt[N][K]^T + bias ----------
// 256x256 tile, BK=32, ring-4 LDS, lead-2 prefetch, 1 barrier + vmcnt(4)/iter,
// mfma_f32_32x32x16_bf16. LDS layout: 128B lines = {row 2L, 2L+1} x 32k,
// logical chunk c = 4*(r&1)+ck stored at physical c ^ (L&7)  (3-bit XOR).
__global__ __launch_bounds__(512, 2) void gemm_kernel(
    const ushort_t* __restrict__ A,    // [M][K] bf16
    const ushort_t* __restrict__ Bt,   // [N][K] bf16
    const float* __restrict__ bias,    // [N]
    float* __restrict__ C) {           // [M][N] f32
  __shared__ __align__(16) ushort_t sA[4 * BUFE];   // 64 KiB
  __shared__ __align__(16) ushort_t sB[4 * BUFE];   // 64 KiB

  const int tid = threadIdx.x;
  const int w   = tid >> 6;          // 0..7
  const int l   = tid & 63;
  const int wm  = w >> 2;            // 0..1  (M half)
  const int wn  = w & 3;             // 0..3  (N quarter)

  // bijective XCD swizzle: 512 blocks, 64 per XCD
  const int orig = blockIdx.x;
  const int lin  = (orig & 7) * 64 + (orig >> 3);
  const int bx   = lin >> 4;         // 0..31  N-block
  const int by   = lin & 15;         // 0..15  M-block
  const int m0   = by * BM;
  const int n0   = bx * BN;

  // ---- fragment read offsets (elements), swizzle folded per-lane ----
  // lane l reads row r = base + (l&31), k-chunk ck = 2s + hi.
  // line L = r>>1, parity p = r&1; logical c = 4p + 2s + hi;
  // physical chunk = c ^ (L&7); base rows are multiples of 32 -> L&7 = (l>>1)&7
  const int rl  = l & 31;
  const int hi  = l >> 5;            // 0..1
  const int le  = (l >> 1) & 7;
  const int p4  = (l & 1) * 4;
  const int phys0 = (p4 + 0 + hi) ^ le;   // s = 0
  const int phys1 = (p4 + 2 + hi) ^ le;   // s = 1
  const int lineoff = (rl >> 1) * 64;     // 64 elem per 128B line
  const int aoff0 = wm * 4096 + lineoff + phys0 * 8;
  const int aoff1 = wm * 4096 + lineoff + phys1 * 8;
  const int boff0 = wn * 2048 + lineoff + phys0 * 8;
  const int boff1 = wn * 2048 + lineoff + phys1 * 8;

  // ---- staging geometry: dest chunk idx (0..1023)/operand, dest = idx*16B
  // (linear; gload_lds-legal). line = idx>>3, physical cp = idx&7,
  // logical c = cp ^ (line&7) -> source row = 2*line + (c>>2), k-off = (c&3)*8
  const int idx0 = tid, idx1 = tid + 512;
  const int c0 = (idx0 & 7) ^ ((idx0 >> 3) & 7);
  const int c1 = (idx1 & 7) ^ ((idx1 >> 3) & 7);
  const int row0 = 2 * (idx0 >> 3) + (c0 >> 2), k0e = (c0 & 3) * 8;
  const int row1 = 2 * (idx1 >> 3) + (c1 >> 2), k1e = (c1 & 3) * 8;
  const ushort_t* gA0 = A  + (size_t)(m0 + row0) * NUM_IN + k0e;
  const ushort_t* gA1 = A  + (size_t)(m0 + row1) * NUM_IN + k1e;
  const ushort_t* gB0 = Bt + (size_t)(n0 + row0) * NUM_IN + k0e;
  const ushort_t* gB1 = Bt + (size_t)(n0 + row1) * NUM_IN + k1e;

#define GLDS(src, dst)                                                         \
  __builtin_amdgcn_global_load_lds(                                            \
      reinterpret_cast<const __attribute__((address_space(1))) uint32_t*>(     \
          (uintptr_t)(src)),                                                   \
      reinterpret_cast<__attribute__((address_space(3))) uint32_t*>(           \
          (uintptr_t)(dst)),                                                   \
      16, 0, 0)

#define STAGE(bs, kt)                                                          \
  {                                                                            \
    GLDS(gA0 + (kt), &sA[(bs) * BUFE + idx0 * 8]);                             \
    GLDS(gA1 + (kt), &sA[(bs) * BUFE + idx1 * 8]);                             \
    GLDS(gB0 + (kt), &sB[(bs) * BUFE + idx0 * 8]);                             \
    GLDS(gB1 + (kt), &sB[(bs) * BUFE + idx1 * 8]);                             \
  }

  f32x16 acc[4][2];
#pragma unroll
  for (int i = 0; i < 4; ++i)
#pragma unroll
    for (int j = 0; j < 2; ++j)
#pragma unroll
      for (int r = 0; r < 16; ++r) acc[i][j][r] = 0.f;

  // ---- prologue: stage tiles 0,1; wait tile 0; tile 1 stays in flight ----
  STAGE(0, 0)
  STAGE(1, BK)
  asm volatile("s_waitcnt vmcnt(4)" ::: "memory");
  __builtin_amdgcn_s_barrier();
  __builtin_amdgcn_sched_barrier(0);

#pragma unroll 1
  for (int t = 0; t < NT; ++t) {
    const int bufo = (t & 3) * BUFE;
    if (t < NT - 2) {
      STAGE((t + 2) & 3, (t + 2) * BK)
    }
    bf16x8 a[4][2], b[2][2];
#pragma unroll
    for (int mi = 0; mi < 4; ++mi) {
      a[mi][0] = *reinterpret_cast<const bf16x8*>(&sA[bufo + aoff0 + mi * 1024]);
      a[mi][1] = *reinterpret_cast<const bf16x8*>(&sA[bufo + aoff1 + mi * 1024]);
    }
#pragma unroll
    for (int ni = 0; ni < 2; ++ni) {
      b[ni][0] = *reinterpret_cast<const bf16x8*>(&sB[bufo + boff0 + ni * 1024]);
      b[ni][1] = *reinterpret_cast<const bf16x8*>(&sB[bufo + boff1 + ni * 1024]);
    }
    __builtin_amdgcn_s_setprio(1);
#pragma unroll
    for (int mi = 0; mi < 4; ++mi)
#pragma unroll
      for (int ni = 0; ni < 2; ++ni) {
        acc[mi][ni] = __builtin_amdgcn_mfma_f32_32x32x16_bf16(
            a[mi][0], b[ni][0], acc[mi][ni], 0, 0, 0);
        acc[mi][ni] = __builtin_amdgcn_mfma_f32_32x32x16_bf16(
            a[mi][1], b[ni][1], acc[mi][ni], 0, 0, 0);
      }
    __builtin_amdgcn_s_setprio(0);
    if (t < NT - 2) {
      asm volatile("s_waitcnt vmcnt(4)" ::: "memory");  // t+1 landed; t+2 flying
    } else {
      asm volatile("s_waitcnt vmcnt(0)" ::: "memory");  // tail drain
    }
    __builtin_amdgcn_s_barrier();
    __builtin_amdgcn_sched_barrier(0);
  }

  // ---- epilogue: C = acc + bias ----
  // D layout (32x32): col = l&31, row = (reg&3) + 8*(reg>>2) + 4*(l>>5)
  const int crow = m0 + wm * 128 + 4 * hi;
  const int ccol = n0 + wn * 64 + rl;
#pragma unroll
  for (int ni = 0; ni < 2; ++ni) {
    const float bi = bias[ccol + ni * 32];
#pragma unroll
    for (int mi = 0; mi < 4; ++mi) {
#pragma unroll
      for (int reg = 0; reg < 16; ++reg) {
        const int r = crow + mi * 32 + (reg & 3) + 8 * (reg >> 2);
        C[(size_t)r * NUM_OUT + ccol + ni * 32] = acc[mi][ni][reg] + bi;
      }
    }
  }
#undef STAGE
#undef GLDS
}

extern "C" void kernel_launch(void* const* d_in, const int* in_sizes, int n_in,
                              void* d_out, int out_size, void* d_ws, size_t ws_size,
                              hipStream_t stream) {
  const float* inputs   = (const float*)d_in[0];  // [4096,2048]
  const float* init_in  = (const float*)d_in[1];  // [2048,1,5]
  const float* init_out = (const float*)d_in[2];  // [1,8192,5]
  const float* in_pos   = (const float*)d_in[3];  // [2048,1,5]
  const float* out_pos  = (const float*)d_in[4];  // [1,8192,5]
  const float* biases   = (const float*)d_in[5];  // [8192]
  float* out = (float*)d_out;                     // [4096,8192]

  ushort_t* Abf = (ushort_t*)d_ws;
  ushort_t* Wt  = (ushort_t*)((char*)d_ws + (size_t)BATCH * NUM_IN * 2);

  cvt_kernel<<<(BATCH * NUM_IN) / (256 * 8), 256, 0, stream>>>(inputs, Abf);
  genw_kernel<<<NUM_OUT / 16, 256, 0, stream>>>(
      in_pos, out_pos, init_in, init_out, Wt);
  gemm_kernel<<<(BATCH / BM) * (NUM_OUT / BN), 512, 0, stream>>>(
      Abf, Wt, biases, out);
}

// Round 5
// 165.838 us; speedup vs baseline: 1.3616x; 1.1173x over previous
//
#include <hip/hip_runtime.h>
#include <hip/hip_bf16.h>
#include <stdint.h>

#define NUM_IN  2048   // K
#define NUM_OUT 8192   // N
#define BATCH   4096   // M
#define SD      5

#define BM 256
#define BN 256
#define BK 64
#define NT (NUM_IN / BK)      // 32 K-tiles
#define NI (NT / 2)           // 16 iterations (2 K-tiles each)
#define TILEE (BM * BK)       // 16384 elements per operand per K-tile

typedef __bf16 bf16x8 __attribute__((ext_vector_type(8)));
typedef float  f32x4  __attribute__((ext_vector_type(4)));
typedef unsigned short ushort_t;
typedef ushort_t ushort8 __attribute__((ext_vector_type(8)));

static __device__ __forceinline__ ushort_t bf16_bits(float f) {
  __hip_bfloat16 h = __float2bfloat16(f);
  ushort_t u;
  __builtin_memcpy(&u, &h, 2);
  return u;
}

// ---------- inputs f32 -> bf16 (vectorized) ----------
__global__ __launch_bounds__(256) void cvt_kernel(const float* __restrict__ x,
                                                  ushort_t* __restrict__ y) {
  const int i = (blockIdx.x * 256 + threadIdx.x) * 8;
  float4 v0 = *reinterpret_cast<const float4*>(x + i);
  float4 v1 = *reinterpret_cast<const float4*>(x + i + 4);
  ushort8 o;
  o[0] = bf16_bits(v0.x); o[1] = bf16_bits(v0.y);
  o[2] = bf16_bits(v0.z); o[3] = bf16_bits(v0.w);
  o[4] = bf16_bits(v1.x); o[5] = bf16_bits(v1.y);
  o[6] = bf16_bits(v1.z); o[7] = bf16_bits(v1.w);
  *reinterpret_cast<ushort8*>(y + i) = o;
}

// ---------- W^T generation: in_pos/init_in staged in LDS ----------
__global__ __launch_bounds__(256) void genw_kernel(
    const float* __restrict__ in_pos, const float* __restrict__ out_pos,
    const float* __restrict__ init_in, const float* __restrict__ init_out,
    ushort_t* __restrict__ Wt) {
  __shared__ float s_ip[NUM_IN * SD];    // 40 KB
  __shared__ float s_iip[NUM_IN * SD];   // 40 KB
  const int tid = threadIdx.x;
#pragma unroll
  for (int i = 0; i < 10; ++i) {
    const int idx = i * 1024 + tid * 4;
    *reinterpret_cast<float4*>(&s_ip[idx]) =
        *reinterpret_cast<const float4*>(in_pos + idx);
    *reinterpret_cast<float4*>(&s_iip[idx]) =
        *reinterpret_cast<const float4*>(init_in + idx);
  }
  __syncthreads();

  const int n  = blockIdx.x * 16 + (tid >> 4);
  const int kg = tid & 15;
  float op[SD], iop[SD];
#pragma unroll
  for (int d = 0; d < SD; ++d) {
    op[d]  = out_pos[n * SD + d];
    iop[d] = init_out[n * SD + d];
  }
#pragma unroll 1
  for (int kb = 0; kb < 16; ++kb) {
    const int k0 = kb * 128 + kg * 8;
    float buf[40], ibuf[40];
#pragma unroll
    for (int j = 0; j < 10; ++j) {
      float4 v = *reinterpret_cast<const float4*>(&s_ip[k0 * SD + j * 4]);
      buf[4 * j + 0] = v.x; buf[4 * j + 1] = v.y;
      buf[4 * j + 2] = v.z; buf[4 * j + 3] = v.w;
      float4 u = *reinterpret_cast<const float4*>(&s_iip[k0 * SD + j * 4]);
      ibuf[4 * j + 0] = u.x; ibuf[4 * j + 1] = u.y;
      ibuf[4 * j + 2] = u.z; ibuf[4 * j + 3] = u.w;
    }
    ushort8 o;
#pragma unroll
    for (int i = 0; i < 8; ++i) {
      float d1 = 0.f, d0 = 0.f;
#pragma unroll
      for (int d = 0; d < SD; ++d) {
        float a = buf[i * SD + d] - op[d];
        float b = ibuf[i * SD + d] - iop[d];
        d1 += a * a;
        d0 += b * b;
      }
      o[i] = bf16_bits(sqrtf(d1) - sqrtf(d0));
    }
    *reinterpret_cast<ushort8*>(Wt + (size_t)n * NUM_IN + k0) = o;
  }
}

// ---------- GEMM: 8-phase 256^2 template (m201 port) ----------
// 2 K-tile double buffer; A tile stored as [mh half: 128 rows][64 k],
// storage row (within half) = wm*64 + rr; B half: storage row = wn*32 + rr.
// 128B rows; 16B chunk c stored at c ^ (row&7)  (round-2 measured-zero swizzle).
__global__ __launch_bounds__(512, 1) void gemm_kernel(
    const ushort_t* __restrict__ A,    // [M][K] bf16
    const ushort_t* __restrict__ Bt,   // [N][K] bf16
    const float* __restrict__ bias,    // [N]
    float* __restrict__ C) {           // [M][N] f32
  __shared__ __align__(16) ushort_t sA[2 * TILEE];   // 64 KiB
  __shared__ __align__(16) ushort_t sB[2 * TILEE];   // 64 KiB

  const int tid  = threadIdx.x;
  const int w    = tid >> 6;         // 0..7
  const int l    = tid & 63;
  const int wm   = w >> 2;           // 0..1
  const int wn   = w & 3;            // 0..3
  const int lrow = l & 15;
  const int lkc  = l >> 4;           // 0..3

  // bijective XCD swizzle (512 = 8*64)
  const int orig = blockIdx.x;
  const int lin  = (orig & 7) * 64 + (orig >> 3);
  const int bx   = lin >> 4;         // 0..31 N-block
  const int by   = lin & 15;         // 0..15 M-block
  const int m0   = by * BM;
  const int n0   = bx * BN;

  // fragment read constants (elements)
  const int ck0 = (lkc ^ (lrow & 7)) * 8;         // kk = 0
  const int ck1 = ((4 + lkc) ^ (lrow & 7)) * 8;   // kk = 1
  const int Ab  = wm * 4096 + lrow * 64;
  const int Bb  = wn * 2048 + lrow * 64;

  // staging geometry: dest chunk d in 0..1023 (d0 = tid, d1 = tid+512)
  // storage row lr = d>>3 (within half), phys chunk p = d&7,
  // logical chunk c = p ^ (lr&7)
  const int d0 = tid, d1 = tid + 512;
  const int lr0 = d0 >> 3, lr1 = d1 >> 3;
  const int c0 = (d0 & 7) ^ (lr0 & 7);
  const int c1 = (d1 & 7) ^ (lr1 & 7);
  // A: global row (half mh) = (lr>>6)*128 + mh*64 + (lr&63)
  const ushort_t* pA0 = A  + (size_t)(m0 + (lr0 >> 6) * 128 + (lr0 & 63)) * NUM_IN + c0 * 8;
  const ushort_t* pA1 = A  + (size_t)(m0 + (lr1 >> 6) * 128 + (lr1 & 63)) * NUM_IN + c1 * 8;
  // B: global row (half nh) = (lr>>5)*64 + nh*32 + (lr&31)
  const ushort_t* pB0 = Bt + (size_t)(n0 + (lr0 >> 5) * 64 + (lr0 & 31)) * NUM_IN + c0 * 8;
  const ushort_t* pB1 = Bt + (size_t)(n0 + (lr1 >> 5) * 64 + (lr1 & 31)) * NUM_IN + c1 * 8;

#define GLDS(src, dst)                                                         \
  __builtin_amdgcn_global_load_lds(                                            \
      reinterpret_cast<const __attribute__((address_space(1))) uint32_t*>(     \
          (uintptr_t)(src)),                                                   \
      reinterpret_cast<__attribute__((address_space(3))) uint32_t*>(           \
          (uintptr_t)(dst)),                                                   \
      16, 0, 0)

#define STAGE_A(bs, mh, kt)                                                    \
  {                                                                            \
    GLDS(pA0 + (size_t)(mh) * 64 * NUM_IN + (kt),                              \
         &sA[(bs) * TILEE + (mh) * 8192 + tid * 8]);                           \
    GLDS(pA1 + (size_t)(mh) * 64 * NUM_IN + (kt),                              \
         &sA[(bs) * TILEE + (mh) * 8192 + tid * 8 + 4096]);                    \
  }
#define STAGE_B(bs, nh, kt)                                                    \
  {                                                                            \
    GLDS(pB0 + (size_t)(nh) * 32 * NUM_IN + (kt),                              \
         &sB[(bs) * TILEE + (nh) * 8192 + tid * 8]);                           \
    GLDS(pB1 + (size_t)(nh) * 32 * NUM_IN + (kt),                              \
         &sB[(bs) * TILEE + (nh) * 8192 + tid * 8 + 4096]);                    \
  }

#define RD_A(bs, mh)                                                           \
  {                                                                            \
    _Pragma("unroll")                                                          \
    for (int mi = 0; mi < 4; ++mi) {                                           \
      a[mi][0] = *reinterpret_cast<const bf16x8*>(                             \
          &sA[(bs) * TILEE + (mh) * 8192 + Ab + mi * 1024 + ck0]);             \
      a[mi][1] = *reinterpret_cast<const bf16x8*>(                             \
          &sA[(bs) * TILEE + (mh) * 8192 + Ab + mi * 1024 + ck1]);             \
    }                                                                          \
  }
#define RD_B(bs, nh, arr)                                                      \
  {                                                                            \
    _Pragma("unroll")                                                          \
    for (int nj = 0; nj < 2; ++nj) {                                           \
      arr[nj][0] = *reinterpret_cast<const bf16x8*>(                           \
          &sB[(bs) * TILEE + (nh) * 8192 + Bb + nj * 1024 + ck0]);             \
      arr[nj][1] = *reinterpret_cast<const bf16x8*>(                           \
          &sB[(bs) * TILEE + (nh) * 8192 + Bb + nj * 1024 + ck1]);             \
    }                                                                          \
  }

#define MFMA_Q(mh, nh, arr)                                                    \
  {                                                                            \
    __builtin_amdgcn_s_setprio(1);                                             \
    _Pragma("unroll")                                                          \
    for (int mi = 0; mi < 4; ++mi)                                             \
      _Pragma("unroll")                                                        \
      for (int nj = 0; nj < 2; ++nj) {                                         \
        acc[(mh) * 4 + mi][(nh) * 2 + nj] =                                    \
            __builtin_amdgcn_mfma_f32_16x16x32_bf16(                           \
                a[mi][0], arr[nj][0], acc[(mh) * 4 + mi][(nh) * 2 + nj],       \
                0, 0, 0);                                                      \
        acc[(mh) * 4 + mi][(nh) * 2 + nj] =                                    \
            __builtin_amdgcn_mfma_f32_16x16x32_bf16(                           \
                a[mi][1], arr[nj][1], acc[(mh) * 4 + mi][(nh) * 2 + nj],       \
                0, 0, 0);                                                      \
      }                                                                        \
    __builtin_amdgcn_s_setprio(0);                                             \
  }

#define BARRIER  __builtin_amdgcn_s_barrier()
#define SCHED0   __builtin_amdgcn_sched_barrier(0)
#define LGKM0    asm volatile("s_waitcnt lgkmcnt(0)" ::: "memory")
#define VMCNT4   asm volatile("s_waitcnt vmcnt(4)" ::: "memory")

  f32x4 acc[8][4];
#pragma unroll
  for (int i = 0; i < 8; ++i)
#pragma unroll
    for (int j = 0; j < 4; ++j) acc[i][j] = f32x4{0.f, 0.f, 0.f, 0.f};

  // ---- prologue: tile0 all 4 halves + tile1 A0,B0; wait tile0 only ----
  STAGE_A(0, 0, 0) STAGE_B(0, 0, 0) STAGE_A(0, 1, 0) STAGE_B(0, 1, 0)
  STAGE_A(1, 0, BK) STAGE_B(1, 0, BK)
  VMCNT4;
  BARRIER;
  SCHED0;

#pragma unroll 1
  for (int it = 0; it < NI; ++it) {
    const int t1k = (2 * it + 1) * BK;
    const int t2  = 2 * it + 2, t3 = 2 * it + 3;
    const int t2k = (t2 < NT ? t2 : NT - 1) * BK;
    const int t3k = (t3 < NT ? t3 : NT - 1) * BK;
    bf16x8 a[4][2], b0[2][2], b1[2][2];

    // p0: read A(buf0,mh0)+B0(buf0); stage A1(tile t1 -> buf1); Q(0,0)
    RD_A(0, 0) RD_B(0, 0, b0)
    STAGE_A(1, 1, t1k)
    BARRIER; LGKM0; SCHED0;
    MFMA_Q(0, 0, b0)
    BARRIER; SCHED0;

    // p1: read B1(buf0); stage B1(t1 -> buf1); Q(0,1)
    RD_B(0, 1, b1)
    STAGE_B(1, 1, t1k)
    BARRIER; LGKM0; SCHED0;
    MFMA_Q(0, 1, b1)
    BARRIER; SCHED0;

    // p2: read A(buf0,mh1); stage A0(t2 -> buf0); Q(1,0)
    RD_A(0, 1)
    STAGE_A(0, 0, t2k)
    BARRIER; LGKM0; SCHED0;
    MFMA_Q(1, 0, b0)
    BARRIER; SCHED0;

    // p3: stage B0(t2 -> buf0); Q(1,1); vmcnt(4)
    STAGE_B(0, 0, t2k)
    BARRIER; SCHED0;
    MFMA_Q(1, 1, b1)
    VMCNT4;
    BARRIER; SCHED0;

    // p4: read A(buf1,mh0)+B0(buf1); stage A1(t2 -> buf0); Q(0,0)
    RD_A(1, 0) RD_B(1, 0, b0)
    STAGE_A(0, 1, t2k)
    BARRIER; LGKM0; SCHED0;
    MFMA_Q(0, 0, b0)
    BARRIER; SCHED0;

    // p5: read B1(buf1); stage B1(t2 -> buf0); Q(0,1)
    RD_B(1, 1, b1)
    STAGE_B(0, 1, t2k)
    BARRIER; LGKM0; SCHED0;
    MFMA_Q(0, 1, b1)
    BARRIER; SCHED0;

    // p6: read A(buf1,mh1); stage A0(t3 -> buf1); Q(1,0)
    RD_A(1, 1)
    STAGE_A(1, 0, t3k)
    BARRIER; LGKM0; SCHED0;
    MFMA_Q(1, 0, b0)
    BARRIER; SCHED0;

    // p7: stage B0(t3 -> buf1); Q(1,1); vmcnt(4)
    STAGE_B(1, 0, t3k)
    BARRIER; SCHED0;
    MFMA_Q(1, 1, b1)
    VMCNT4;
    BARRIER; SCHED0;
  }

  // ---- epilogue: C = acc + bias ----
  const int er = l >> 4;          // 0..3
  const int ec = l & 15;
#pragma unroll
  for (int nh = 0; nh < 2; ++nh) {
#pragma unroll
    for (int nj = 0; nj < 2; ++nj) {
      const int col = n0 + wn * 64 + nh * 32 + nj * 16 + ec;
      const float bi = bias[col];
#pragma unroll
      for (int mh = 0; mh < 2; ++mh) {
#pragma unroll
        for (int mi = 0; mi < 4; ++mi) {
#pragma unroll
          for (int j = 0; j < 4; ++j) {
            const int row = m0 + wm * 128 + mh * 64 + mi * 16 + er * 4 + j;
            C[(size_t)row * NUM_OUT + col] =
                acc[mh * 4 + mi][nh * 2 + nj][j] + bi;
          }
        }
      }
    }
  }
#undef STAGE_A
#undef STAGE_B
#undef RD_A
#undef RD_B
#undef MFMA_Q
#undef GLDS
}

extern "C" void kernel_launch(void* const* d_in, const int* in_sizes, int n_in,
                              void* d_out, int out_size, void* d_ws, size_t ws_size,
                              hipStream_t stream) {
  const float* inputs   = (const float*)d_in[0];  // [4096,2048]
  const float* init_in  = (const float*)d_in[1];  // [2048,1,5]
  const float* init_out = (const float*)d_in[2];  // [1,8192,5]
  const float* in_pos   = (const float*)d_in[3];  // [2048,1,5]
  const float* out_pos  = (const float*)d_in[4];  // [1,8192,5]
  const float* biases   = (const float*)d_in[5];  // [8192]
  float* out = (float*)d_out;                     // [4096,8192]

  ushort_t* Abf = (ushort_t*)d_ws;
  ushort_t* Wt  = (ushort_t*)((char*)d_ws + (size_t)BATCH * NUM_IN * 2);

  cvt_kernel<<<(BATCH * NUM_IN) / (256 * 8), 256, 0, stream>>>(inputs, Abf);
  genw_kernel<<<NUM_OUT / 16, 256, 0, stream>>>(
      in_pos, out_pos, init_in, init_out, Wt);
  gemm_kernel<<<(BATCH / BM) * (NUM_OUT / BN), 512, 0, stream>>>(
      Abf, Wt, biases, out);
}